// Round 7
// baseline (30.357 us; speedup 1.0000x reference)
//
#include <hip/hip_runtime.h>
#include <math.h>

#define HIDDEN 2048
#define IN_F 350

__device__ __forceinline__ float sigmoidf_(float v) { return 1.0f / (1.0f + expf(-v)); }
__device__ __forceinline__ float dot4_(float4 a, float4 b) {
    return a.x*b.x + a.y*b.y + a.z*b.z + a.w*b.w;
}

// K1: feat + LSTM layer 0 (h=c=0 => f-gate dead, W_hh unused).
// 512 blocks x 768 thr (12 waves). Block b owns units [4b,4b+4); wave w ->
// (unit 4b + w/3, gate w%3). Also seeds out[r] = fc_b[r] (stream-ordered
// before K2's fc atomicAdds).
__global__ __launch_bounds__(768) void k1_feat_lstm0(
    const float* __restrict__ x, const float* __restrict__ Wih,
    const float* __restrict__ bih, const float* __restrict__ bhh,
    const float* __restrict__ fcb, float* __restrict__ h1,
    float* __restrict__ out)
{
    __shared__ __align__(16) float feat[IN_F];
    __shared__ float hx[84];     // hands, contiguous copy of x[182..265]
    __shared__ float sc[12];     // 4 source points (8) + dl/dr (4)
    __shared__ float ext[4];     // wl, hl, wr, hr
    __shared__ float gd[12];
    const int tid = threadIdx.x, wave = tid >> 6, lane = tid & 63;
    const int b = blockIdx.x;

    if (b < IN_F && tid == 767) out[b] = fcb[b];          // seed fc bias

    if (tid < 84) hx[tid] = x[182 + tid];
    else if (tid >= 128 && tid < 136) {
        int t = tid - 128;
        int p = t >> 1;                                   // body,face,left,right
        int base = (p == 0) ? 0 : (p == 1) ? 106 : (p == 2) ? 200 : 242;
        sc[t] = x[base + (t & 1)];
    }
    __syncthreads();
    if (tid < 4) {                                        // extrema: (hand, coord)
        const int h = tid >> 1, c = tid & 1;
        float m = hx[h*42 + c], M = m;
        #pragma unroll
        for (int jj = 1; jj < 21; ++jj) {
            float v = hx[h*42 + 2*jj + c];
            m = fminf(m, v); M = fmaxf(M, v);
        }
        ext[tid] = M - m;
    }
    __syncthreads();
    if (tid < 4) {
        const int h = tid >> 1;
        bool ok = (ext[2*h] != 0.0f) && (ext[2*h + 1] != 0.0f);
        sc[8 + tid] = ok ? ext[tid] : 1.0f;
    }
    __syncthreads();
    if (tid < 133) {
        const float sbx = sc[0], sby = sc[1], sfx = sc[2], sfy = sc[3];
        const float slx = sc[4], sly = sc[5], srx = sc[6], sry = sc[7];
        const float dlx = sc[8], dly = sc[9], drx = sc[10], dry = sc[11];
        const int k = tid;
        float vx = x[2*k], vy = x[2*k + 1];
        if (k < 17) {                 // body
            feat[2*k]   = vx - sbx;  feat[2*k+1] = vy - sby;
        } else if (k < 23) {          // feet
            feat[2*k]   = vx;        feat[2*k+1] = vy;
        } else if (k < 91) {          // face
            feat[2*k]   = vx - sfx;  feat[2*k+1] = vy - sfy;
        } else if (k < 112) {         // left hand + chin2l
            int jj = k - 91;
            feat[182 + 2*jj] = (vx - slx) / dlx;  feat[183 + 2*jj] = (vy - sly) / dly;
            feat[266 + 2*jj] = vx - sbx;          feat[267 + 2*jj] = vy - sby;
        } else {                      // right hand + chin2r
            int jj = k - 112;
            feat[224 + 2*jj] = (vx - srx) / drx;  feat[225 + 2*jj] = (vy - sry) / dry;
            feat[308 + 2*jj] = vx - sbx;          feat[309 + 2*jj] = vy - sby;
        }
    }
    __syncthreads();

    // wave w: unit u = 4b + w/3, gate = w%3 -> row {0,2,3}[gate]*H + u
    const int u = b * 4 + wave / 3;
    const int gate = wave % 3;
    const int grow = ((gate == 0) ? 0 : (gate == 1) ? 2 : 3) * HIDDEN + u;
    const float2* wr = (const float2*)(Wih + (size_t)grow * IN_F);
    const float2* f2 = (const float2*)feat;
    const bool has2 = (128 + lane) < 175;
    float2 w0 = wr[lane];
    float2 w1 = wr[64 + lane];
    float2 w2 = has2 ? wr[128 + lane] : make_float2(0.f, 0.f);
    float2 f0 = f2[lane];
    float2 f1 = f2[64 + lane];
    float2 fx = has2 ? f2[128 + lane] : make_float2(0.f, 0.f);
    float acc = w0.x*f0.x + w0.y*f0.y + w1.x*f1.x + w1.y*f1.y + w2.x*fx.x + w2.y*fx.y;
    #pragma unroll
    for (int off = 32; off; off >>= 1) acc += __shfl_down(acc, off);
    if (lane == 0) gd[wave] = acc + bih[grow] + bhh[grow];
    __syncthreads();
    if (tid < 4) {
        float c = sigmoidf_(gd[3*tid + 0]) * tanhf(gd[3*tid + 1]);
        h1[b*4 + tid] = sigmoidf_(gd[3*tid + 2]) * tanhf(c);
    }
}

// K2: LSTM layer 1 (h=c=0 again) + fused fc partial. 512 blocks x 768 thr
// (12 waves = 4 units x 3 gates, 2 blocks/CU = 24 waves/CU).
// h1 staged in LDS; weight rows: 8 float4/lane, all hoisted (deep ILP).
// fc: block b adds fcw[r, 4b..4b+4) . h2_local to out[r] (seeded by K1).
__global__ __launch_bounds__(768) void k2_lstm1_fc(
    const float* __restrict__ Wih, const float* __restrict__ bih,
    const float* __restrict__ bhh, const float* __restrict__ fcw,
    const float* __restrict__ h1, float* __restrict__ out)
{
    __shared__ __align__(16) float h1s[HIDDEN];
    __shared__ float gd[12];
    __shared__ __align__(16) float h2s[4];
    const int tid = threadIdx.x, wave = tid >> 6, lane = tid & 63;
    const int b = blockIdx.x;

    {   // stage h1: 512 float4 over 768 threads
        const float4* h4g = (const float4*)h1;
        float4* h4s = (float4*)h1s;
        if (tid < 512) h4s[tid] = h4g[tid];
    }
    __syncthreads();

    const int u = b * 4 + wave / 3;
    const int gate = wave % 3;
    const int grow = ((gate == 0) ? 0 : (gate == 1) ? 2 : 3) * HIDDEN + u;
    const float4* wr = (const float4*)(Wih + (size_t)grow * HIDDEN);
    const float4* h4 = (const float4*)h1s;

    float4 wv0 = wr[lane];
    float4 wv1 = wr[ 64 + lane];
    float4 wv2 = wr[128 + lane];
    float4 wv3 = wr[192 + lane];
    float4 wv4 = wr[256 + lane];
    float4 wv5 = wr[320 + lane];
    float4 wv6 = wr[384 + lane];
    float4 wv7 = wr[448 + lane];

    float acc = dot4_(wv0, h4[lane])       + dot4_(wv1, h4[ 64 + lane])
              + dot4_(wv2, h4[128 + lane]) + dot4_(wv3, h4[192 + lane])
              + dot4_(wv4, h4[256 + lane]) + dot4_(wv5, h4[320 + lane])
              + dot4_(wv6, h4[384 + lane]) + dot4_(wv7, h4[448 + lane]);
    #pragma unroll
    for (int off = 32; off; off >>= 1) acc += __shfl_down(acc, off);
    if (lane == 0) gd[wave] = acc + bih[grow] + bhh[grow];
    __syncthreads();
    if (tid < 4) {
        float c = sigmoidf_(gd[3*tid + 0]) * tanhf(gd[3*tid + 1]);
        h2s[tid] = sigmoidf_(gd[3*tid + 2]) * tanhf(c);   // h2 stays in LDS
    }
    __syncthreads();

    // fused fc partial: thread r handles row r with this block's 4 columns
    if (tid < IN_F) {
        float4 w = *(const float4*)(fcw + (size_t)tid * HIDDEN + b * 4);
        float4 h2v = *(const float4*)h2s;
        atomicAdd(&out[tid], dot4_(w, h2v));
    }
}

extern "C" void kernel_launch(void* const* d_in, const int* in_sizes, int n_in,
                              void* d_out, int out_size, void* d_ws, size_t ws_size,
                              hipStream_t stream) {
    const float* x     = (const float*)d_in[0];
    const float* W_ih0 = (const float*)d_in[1];
    // d_in[2] = W_hh0 : unused (h0 == 0)
    const float* b_ih0 = (const float*)d_in[3];
    const float* b_hh0 = (const float*)d_in[4];
    const float* W_ih1 = (const float*)d_in[5];
    // d_in[6] = W_hh1 : unused (h == 0 for cell 2 as well)
    const float* b_ih1 = (const float*)d_in[7];
    const float* b_hh1 = (const float*)d_in[8];
    const float* fc_w  = (const float*)d_in[9];
    const float* fc_b  = (const float*)d_in[10];

    float* h1 = (float*)d_ws;            // 2048 floats

    k1_feat_lstm0<<<512, 768, 0, stream>>>(x, W_ih0, b_ih0, b_hh0, fc_b, h1,
                                           (float*)d_out);
    k2_lstm1_fc<<<512, 768, 0, stream>>>(W_ih1, b_ih1, b_hh1, fc_w, h1,
                                         (float*)d_out);
}